// Round 7
// baseline (239.989 us; speedup 1.0000x reference)
//
#include <hip/hip_runtime.h>

#define KTAGS 11
#define SS    13
#define TT    1024
#define BB    4096
#define GPW   4      // chains per 64-thread block (16 lanes per chain)
#define PF    8      // prefetch pipeline depth (1023 % 8 == 7 -> tail = PF-1)

__global__ __launch_bounds__(64)
void crf_scan_kernel(const float* __restrict__ e,
                     const float* __restrict__ Tmat,
                     const int*   __restrict__ tags,
                     float*       __restrict__ out_per_b)
{
    __shared__ float sT[SS * SS];
    const int tid = threadIdx.x;
    for (int i = tid; i < SS * SS; i += 64) sT[i] = Tmat[i];

    const int g   = tid >> 4;          // chain within wave
    const int to  = tid & 15;          // state owned by lane (0..10 real, 11..15 pad)
    const int toT = (to < SS) ? to : (SS - 1);       // clamped T column
    const int toE = (to < KTAGS) ? to : (KTAGS - 1); // clamped e column
    const int b   = blockIdx.x * GPW + g;

    __syncthreads();   // sT staged (only barrier)

    // Rotation-indexed M: W[r] multiplies ror_r(alpha)[to] = alpha[(to - r) & 15].
    // W[r] = exp(T[f][to]) with f = (to-r)&15, zero when f >= 11 or lane is pad.
    // (Verified correct in rounds 5/6: absmax 0.0.)
    float W[16];
#pragma unroll
    for (int r = 0; r < 16; ++r) {
        const int f = (to - r) & 15;
        W[r] = (f < KTAGS && to <= SS - 1 && to != KTAGS)
                 ? __expf(sT[f * SS + toT]) : 0.f;
        if (to >= SS) W[r] = 0.f;
    }
    const float eTstop = __expf(sT[toT * SS + (SS - 1)]);

    const float* pe  = e    + (size_t)b * TT * KTAGS + toE;
    const int*   tgp = tags + (size_t)b * TT;

    // ---------------- t = 0 ----------------
    const float e0 = pe[0];
    const int   tg0 = tgp[0];
    float aP = (to < SS) ? __expf(sT[(SS - 2) * SS + toT] + e0) : 0.f;

    float cacc = 0.f;
    const float gold0 = sT[(SS - 2) * SS + tg0];
    float em_acc    = (to == tg0) ? e0 : 0.f;
    float trans_acc = 0.f;

    // ---------------- register prefetch pipeline ----------------
    // trvbuf[j] = T[tag_{t-1}, tag_t] for the step in slot j: looked up PF steps
    // ahead of use, so the ds_read latency is fully hidden (the round-6 stall).
    float ebuf[PF], trvbuf[PF];
    int   tbuf[PF];
    {
        int tprev = tg0;
#pragma unroll
        for (int j = 0; j < PF; ++j) {
            ebuf[j] = pe[(size_t)(1 + j) * KTAGS];
            const int tcur = tgp[1 + j];
            tbuf[j]   = tcur;
            trvbuf[j] = sT[tprev * SS + tcur];
            tprev = tcur;
        }
    }
    int tgl = tgp[PF];   // tag-chain head of the prefetch strand (last prefetched tag)

    float scP = 1.f, eeP = 0.f;   // delayed exact power-of-two rescale

// One fused rotate-multiply-accumulate block: 4 DPP muls + 12 DPP fmacs.
// s_nop 1 covers the VALU-write -> DPP-read hazard on aP.
#define STEP(J, E_T, TG, TRV)                                                  \
    {                                                                          \
        const float X_T = __expf(E_T);   /* issues early, hides under fmacs */ \
        float ac0, ac1, ac2, ac3;                                              \
        asm volatile(                                                          \
          "s_nop 1\n\t"                                                        \
          "v_mul_f32 %0, %4, %5\n\t"                                           \
          "v_mul_f32_dpp %1, %4, %6  row_ror:1  row_mask:0xf bank_mask:0xf\n\t"\
          "v_mul_f32_dpp %2, %4, %7  row_ror:2  row_mask:0xf bank_mask:0xf\n\t"\
          "v_mul_f32_dpp %3, %4, %8  row_ror:3  row_mask:0xf bank_mask:0xf\n\t"\
          "v_fmac_f32_dpp %0, %4, %9  row_ror:4  row_mask:0xf bank_mask:0xf\n\t"\
          "v_fmac_f32_dpp %1, %4, %10 row_ror:5  row_mask:0xf bank_mask:0xf\n\t"\
          "v_fmac_f32_dpp %2, %4, %11 row_ror:6  row_mask:0xf bank_mask:0xf\n\t"\
          "v_fmac_f32_dpp %3, %4, %12 row_ror:7  row_mask:0xf bank_mask:0xf\n\t"\
          "v_fmac_f32_dpp %0, %4, %13 row_ror:8  row_mask:0xf bank_mask:0xf\n\t"\
          "v_fmac_f32_dpp %1, %4, %14 row_ror:9  row_mask:0xf bank_mask:0xf\n\t"\
          "v_fmac_f32_dpp %2, %4, %15 row_ror:10 row_mask:0xf bank_mask:0xf\n\t"\
          "v_fmac_f32_dpp %3, %4, %16 row_ror:11 row_mask:0xf bank_mask:0xf\n\t"\
          "v_fmac_f32_dpp %0, %4, %17 row_ror:12 row_mask:0xf bank_mask:0xf\n\t"\
          "v_fmac_f32_dpp %1, %4, %18 row_ror:13 row_mask:0xf bank_mask:0xf\n\t"\
          "v_fmac_f32_dpp %2, %4, %19 row_ror:14 row_mask:0xf bank_mask:0xf\n\t"\
          "v_fmac_f32_dpp %3, %4, %20 row_ror:15 row_mask:0xf bank_mask:0xf\n\t"\
          : "=&v"(ac0), "=&v"(ac1), "=&v"(ac2), "=&v"(ac3)                     \
          : "v"(aP), "v"(W[0]), "v"(W[1]), "v"(W[2]),  "v"(W[3]),              \
            "v"(W[4]), "v"(W[5]), "v"(W[6]),  "v"(W[7]), "v"(W[8]),            \
            "v"(W[9]), "v"(W[10]), "v"(W[11]), "v"(W[12]), "v"(W[13]),         \
            "v"(W[14]), "v"(W[15]));                                           \
        float xsc = X_T;                                                       \
        if (((J) & 3) == 0) { cacc += eeP * 0.6931471805599453f; xsc *= scP; } \
        aP = ((ac0 + ac1) + (ac2 + ac3)) * xsc;                                \
        if (((J) & 3) == 3) {   /* sample post-update alphas, apply next J&3==0 */ \
            float mm;                                                          \
            asm volatile(                                                      \
              "s_nop 1\n\t"                                                    \
              "v_max_f32_dpp %0, %1, %1 row_ror:8 row_mask:0xf bank_mask:0xf\n\t"\
              "s_nop 1\n\t"                                                    \
              "v_max_f32_dpp %0, %0, %0 row_ror:4 row_mask:0xf bank_mask:0xf\n\t"\
              "s_nop 1\n\t"                                                    \
              "v_max_f32_dpp %0, %0, %0 quad_perm:[1,0,3,2] row_mask:0xf bank_mask:0xf\n\t"\
              "s_nop 1\n\t"                                                    \
              "v_max_f32_dpp %0, %0, %0 quad_perm:[2,3,0,1] row_mask:0xf bank_mask:0xf\n\t"\
              : "=&v"(mm) : "v"(aP));                                          \
            const int ee = (int)((__float_as_uint(mm) >> 23) & 0xFFu) - 127;   \
            scP = __uint_as_float((unsigned)(127 - ee) << 23);                 \
            eeP = (float)ee;                                                   \
        }                                                                      \
        em_acc    += (to == (TG)) ? (E_T) : 0.f;                               \
        trans_acc += (TRV);                                                    \
    }

    const float* qe = pe  + (size_t)(1 + PF) * KTAGS;   // next-block prefetch source
    const int*   qt = tgp + 1 + PF;

    int tb = 1;
    for (; tb + 2 * PF <= TT; tb += PF) {   // tb = 1..1001: steps 1..1008
#pragma unroll
        for (int j = 0; j < PF; ++j) {
            const float E_T = ebuf[j];
            const int   TG  = tbuf[j];
            const float TRV = trvbuf[j];
            ebuf[j] = qe[j * KTAGS];        // compile-time offsets; pointer bumped per block
            const int tg_new = qt[j];
            tbuf[j]   = tg_new;
            trvbuf[j] = sT[tgl * SS + tg_new];   // ds_read issued PF steps early
            tgl = tg_new;
            STEP(j, E_T, TG, TRV)
        }
        qe += (size_t)PF * KTAGS; qt += PF;
    }

    // penultimate block: steps 1009..1016, prefetch only 7 (steps 1017..1023)
#pragma unroll
    for (int j = 0; j < PF; ++j) {
        const float E_T = ebuf[j];
        const int   TG  = tbuf[j];
        const float TRV = trvbuf[j];
        if (j < PF - 1) {
            ebuf[j] = qe[j * KTAGS];
            const int tg_new = qt[j];
            tbuf[j]   = tg_new;
            trvbuf[j] = sT[tgl * SS + tg_new];
            tgl = tg_new;
        }
        STEP(j, E_T, TG, TRV)
    }

    // tail: steps 1017..1023 from slots 0..6
#pragma unroll
    for (int j = 0; j < PF - 1; ++j) {
        STEP(j, ebuf[j], tbuf[j], trvbuf[j])
    }
#undef STEP

    // ---------------- epilogue: 16-lane reductions ----------------
    // tgl ended as tgp[1023] (last prefetched tag == last step's tag).
    float z  = (to < KTAGS) ? aP * eTstop : 0.f;
    float em = em_acc;
#pragma unroll
    for (int s = 8; s >= 1; s >>= 1) {
        z  += __shfl_xor(z,  s, 16);
        em += __shfl_xor(em, s, 16);
    }
    if (to == 0) {
        const float logZ = cacc + __logf(z);
        const float gold = gold0 + em + trans_acc + sT[tgl * SS + (SS - 1)];
        out_per_b[b] = logZ - gold;
    }
}

// Deterministic mean over B values (double accumulation).
__global__ __launch_bounds__(256)
void reduce_mean_kernel(const float* __restrict__ v, float* __restrict__ out, int n)
{
    __shared__ double sbuf[256];
    double s = 0.0;
    for (int i = threadIdx.x; i < n; i += 256) s += (double)v[i];
    sbuf[threadIdx.x] = s;
    __syncthreads();
    for (int k = 128; k > 0; k >>= 1) {
        if ((int)threadIdx.x < k) sbuf[threadIdx.x] += sbuf[threadIdx.x + k];
        __syncthreads();
    }
    if (threadIdx.x == 0) out[0] = (float)(sbuf[0] / (double)n);
}

extern "C" void kernel_launch(void* const* d_in, const int* in_sizes, int n_in,
                              void* d_out, int out_size, void* d_ws, size_t ws_size,
                              hipStream_t stream)
{
    const float* e    = (const float*)d_in[0];
    const float* Tmat = (const float*)d_in[1];
    const int*   tags = (const int*)d_in[2];
    // d_in[3] = mask: all-true in this problem; kernel implements the all-true path.

    float* ws  = (float*)d_ws;       // BB floats of scratch
    float* out = (float*)d_out;

    crf_scan_kernel<<<BB / GPW, 64, 0, stream>>>(e, Tmat, tags, ws);
    reduce_mean_kernel<<<1, 256, 0, stream>>>(ws, out, BB);
}

// Round 8
// 100.166 us; speedup vs baseline: 2.3959x; 2.3959x over previous
//
#include <hip/hip_runtime.h>

#define KTAGS 11
#define SS    13
#define TT    1024
#define BB    4096
#define GPW   4      // chains per 64-thread block (16 lanes per chain)
#define UNR   16     // steps per unrolled block == e/tags pipeline depth

__global__ __launch_bounds__(64)
void crf_scan_kernel(const float* __restrict__ e,
                     const float* __restrict__ Tmat,
                     const int*   __restrict__ tags,
                     float*       __restrict__ out_per_b)
{
    __shared__ float sT[SS * SS];
    const int tid = threadIdx.x;
    for (int i = tid; i < SS * SS; i += 64) sT[i] = Tmat[i];

    const int g   = tid >> 4;          // chain within wave
    const int to  = tid & 15;          // state owned by lane (0..10 real, 11..15 pad)
    const int toT = (to < SS) ? to : (SS - 1);       // clamped T column
    const int toE = (to < KTAGS) ? to : (KTAGS - 1); // clamped e column
    const int b   = blockIdx.x * GPW + g;

    __syncthreads();   // sT staged (only barrier)

    // Rotation-indexed M: W[r] multiplies ror_r(alpha)[to] = alpha[(to - r) & 15].
    // (Verified rounds 5-7: absmax 0.0.)
    float W[16];
#pragma unroll
    for (int r = 0; r < 16; ++r) {
        const int f = (to - r) & 15;
        W[r] = (f < KTAGS && to <= SS - 1 && to != KTAGS)
                 ? __expf(sT[f * SS + toT]) : 0.f;
        if (to >= SS) W[r] = 0.f;
    }
    const float eTstop = __expf(sT[toT * SS + (SS - 1)]);

    const float* pe  = e    + (size_t)b * TT * KTAGS + toE;
    const int*   tgp = tags + (size_t)b * TT;

    // ---------------- t = 0 ----------------
    const float e0  = pe[0];
    const int   tg0 = tgp[0];
    float aP = (to < SS) ? __expf(sT[(SS - 2) * SS + toT] + e0) : 0.f;

    float cacc = 0.f;
    const float gold0 = sT[(SS - 2) * SS + tg0];
    float em_acc    = (to == tg0) ? e0 : 0.f;
    float trans_acc = 0.f;

    // ---------------- pipelines ----------------
    // e lead = 16 steps, tags lead = 16 steps, trv (LDS) lead = 4 steps.
    // trv addresses only ever use tbuf entries >= 12 steps old.
    float ebuf[UNR];
    int   tbuf[UNR];
    float trv4[4];
#pragma unroll
    for (int j = 0; j < UNR; ++j) {
        ebuf[j] = pe[(size_t)(1 + j) * KTAGS];
        tbuf[j] = tgp[1 + j];
    }
    {
        int tA = tg0;
#pragma unroll
        for (int j = 0; j < 4; ++j) {            // trv for steps 1..4
            const int tB = tbuf[j];
            trv4[j] = sT[tA * SS + tB];
            tA = tB;
        }
    }

    float scP = 1.f, eeP = 0.f;   // delayed exact power-of-two rescale

// Fused rotate-multiply-accumulate: 4 DPP muls + 12 DPP fmacs (verified).
#define STEP(J, E_T, TG, TRV)                                                  \
    {                                                                          \
        const float X_T = __expf(E_T);   /* hides under the fmac chain */      \
        float ac0, ac1, ac2, ac3;                                              \
        asm volatile(                                                          \
          "s_nop 1\n\t"                                                        \
          "v_mul_f32 %0, %4, %5\n\t"                                           \
          "v_mul_f32_dpp %1, %4, %6  row_ror:1  row_mask:0xf bank_mask:0xf\n\t"\
          "v_mul_f32_dpp %2, %4, %7  row_ror:2  row_mask:0xf bank_mask:0xf\n\t"\
          "v_mul_f32_dpp %3, %4, %8  row_ror:3  row_mask:0xf bank_mask:0xf\n\t"\
          "v_fmac_f32_dpp %0, %4, %9  row_ror:4  row_mask:0xf bank_mask:0xf\n\t"\
          "v_fmac_f32_dpp %1, %4, %10 row_ror:5  row_mask:0xf bank_mask:0xf\n\t"\
          "v_fmac_f32_dpp %2, %4, %11 row_ror:6  row_mask:0xf bank_mask:0xf\n\t"\
          "v_fmac_f32_dpp %3, %4, %12 row_ror:7  row_mask:0xf bank_mask:0xf\n\t"\
          "v_fmac_f32_dpp %0, %4, %13 row_ror:8  row_mask:0xf bank_mask:0xf\n\t"\
          "v_fmac_f32_dpp %1, %4, %14 row_ror:9  row_mask:0xf bank_mask:0xf\n\t"\
          "v_fmac_f32_dpp %2, %4, %15 row_ror:10 row_mask:0xf bank_mask:0xf\n\t"\
          "v_fmac_f32_dpp %3, %4, %16 row_ror:11 row_mask:0xf bank_mask:0xf\n\t"\
          "v_fmac_f32_dpp %0, %4, %17 row_ror:12 row_mask:0xf bank_mask:0xf\n\t"\
          "v_fmac_f32_dpp %1, %4, %18 row_ror:13 row_mask:0xf bank_mask:0xf\n\t"\
          "v_fmac_f32_dpp %2, %4, %19 row_ror:14 row_mask:0xf bank_mask:0xf\n\t"\
          "v_fmac_f32_dpp %3, %4, %20 row_ror:15 row_mask:0xf bank_mask:0xf\n\t"\
          : "=&v"(ac0), "=&v"(ac1), "=&v"(ac2), "=&v"(ac3)                     \
          : "v"(aP), "v"(W[0]), "v"(W[1]), "v"(W[2]),  "v"(W[3]),              \
            "v"(W[4]), "v"(W[5]), "v"(W[6]),  "v"(W[7]), "v"(W[8]),            \
            "v"(W[9]), "v"(W[10]), "v"(W[11]), "v"(W[12]), "v"(W[13]),         \
            "v"(W[14]), "v"(W[15]));                                           \
        float xsc = X_T;                                                       \
        if (((J) & 3) == 0) { cacc += eeP * 0.6931471805599453f; xsc *= scP; } \
        aP = ((ac0 + ac1) + (ac2 + ac3)) * xsc;                                \
        if (((J) & 3) == 3) {   /* sample post-update alphas; apply at next (J&3)==0 */ \
            float mm;                                                          \
            asm volatile(                                                      \
              "s_nop 1\n\t"                                                    \
              "v_max_f32_dpp %0, %1, %1 row_ror:8 row_mask:0xf bank_mask:0xf\n\t"\
              "s_nop 1\n\t"                                                    \
              "v_max_f32_dpp %0, %0, %0 row_ror:4 row_mask:0xf bank_mask:0xf\n\t"\
              "s_nop 1\n\t"                                                    \
              "v_max_f32_dpp %0, %0, %0 quad_perm:[1,0,3,2] row_mask:0xf bank_mask:0xf\n\t"\
              "s_nop 1\n\t"                                                    \
              "v_max_f32_dpp %0, %0, %0 quad_perm:[2,3,0,1] row_mask:0xf bank_mask:0xf\n\t"\
              : "=&v"(mm) : "v"(aP));                                          \
            const int ee = (int)((__float_as_uint(mm) >> 23) & 0xFFu) - 127;   \
            scP = __uint_as_float((unsigned)(127 - ee) << 23);                 \
            eeP = (float)ee;                                                   \
        }                                                                      \
        em_acc    += (to == (TG)) ? (E_T) : 0.f;                               \
        trans_acc += (TRV);                                                    \
    }

    const float* qe = pe  + (size_t)(1 + UNR) * KTAGS;   // refill source: e[17...]
    const int*   qt = tgp + 1 + UNR;                      // refill source: tags[17...]

    // main loop: steps 1..992 (full refills valid: t+16 <= 1008 <= 1023)
    for (int tb = 1; tb + 2 * UNR <= TT; tb += UNR) {
#pragma unroll
        for (int j = 0; j < UNR; ++j) {
            const float E_T = ebuf[j];
            const int   TG  = tbuf[j];
            const float TRV = trv4[j & 3];
            ebuf[j] = qe[j * KTAGS];          // e[t+16]
            tbuf[j] = qt[j];                  // tags[t+16]
            // trv for step t+4: addresses are 12/13-step-old register values
            trv4[j & 3] = sT[tbuf[(j + 3) & 15] * SS + tbuf[(j + 4) & 15]];
            STEP(j, E_T, TG, TRV)
        }
        qe += (size_t)UNR * KTAGS; qt += UNR;
    }

    // penultimate block: steps 993..1008; refill only j<15 (tags/e[1009..1023])
#pragma unroll
    for (int j = 0; j < UNR; ++j) {
        const float E_T = ebuf[j];
        const int   TG  = tbuf[j];
        const float TRV = trv4[j & 3];
        if (j < UNR - 1) {
            ebuf[j] = qe[j * KTAGS];
            tbuf[j] = qt[j];
        }
        trv4[j & 3] = sT[tbuf[(j + 3) & 15] * SS + tbuf[(j + 4) & 15]];
        STEP(j, E_T, TG, TRV)
    }

    // tail: steps 1009..1023 (j = 0..14); trv compute only while consumers remain
#pragma unroll
    for (int j = 0; j < UNR - 1; ++j) {
        const float E_T = ebuf[j];
        const int   TG  = tbuf[j];
        const float TRV = trv4[j & 3];
        if (j <= 10) {   // trv for steps 1013..1023; j=11.. would read stale slot 15
            trv4[j & 3] = sT[tbuf[(j + 3) & 15] * SS + tbuf[(j + 4) & 15]];
        }
        STEP(j, E_T, TG, TRV)
    }
#undef STEP

    // ---------------- epilogue: 16-lane reductions ----------------
    const int tg_last = tbuf[14];   // tags[1023] (refilled in penultimate, j=14)
    float z  = (to < KTAGS) ? aP * eTstop : 0.f;
    float em = em_acc;
#pragma unroll
    for (int s = 8; s >= 1; s >>= 1) {
        z  += __shfl_xor(z,  s, 16);
        em += __shfl_xor(em, s, 16);
    }
    if (to == 0) {
        const float logZ = cacc + __logf(z);
        const float gold = gold0 + em + trans_acc + sT[tg_last * SS + (SS - 1)];
        out_per_b[b] = logZ - gold;
    }
}

// Deterministic mean over B values (double accumulation).
__global__ __launch_bounds__(256)
void reduce_mean_kernel(const float* __restrict__ v, float* __restrict__ out, int n)
{
    __shared__ double sbuf[256];
    double s = 0.0;
    for (int i = threadIdx.x; i < n; i += 256) s += (double)v[i];
    sbuf[threadIdx.x] = s;
    __syncthreads();
    for (int k = 128; k > 0; k >>= 1) {
        if ((int)threadIdx.x < k) sbuf[threadIdx.x] += sbuf[threadIdx.x + k];
        __syncthreads();
    }
    if (threadIdx.x == 0) out[0] = (float)(sbuf[0] / (double)n);
}

extern "C" void kernel_launch(void* const* d_in, const int* in_sizes, int n_in,
                              void* d_out, int out_size, void* d_ws, size_t ws_size,
                              hipStream_t stream)
{
    const float* e    = (const float*)d_in[0];
    const float* Tmat = (const float*)d_in[1];
    const int*   tags = (const int*)d_in[2];
    // d_in[3] = mask: all-true in this problem; kernel implements the all-true path.

    float* ws  = (float*)d_ws;       // BB floats of scratch
    float* out = (float*)d_out;

    crf_scan_kernel<<<BB / GPW, 64, 0, stream>>>(e, Tmat, tags, ws);
    reduce_mean_kernel<<<1, 256, 0, stream>>>(ws, out, BB);
}

// Round 9
// 96.869 us; speedup vs baseline: 2.4775x; 1.0340x over previous
//
#include <hip/hip_runtime.h>

#define KTAGS 11
#define SS    13
#define TT    1024
#define BB    4096
#define GPW   4      // chains per 64-thread block (16 lanes per chain)
#define UNR   16     // steps per unrolled block == e/tags pipeline depth

// ---------------------------------------------------------------------------
// Kernel 1: forward scan (logZ) + emission gather. NO LDS access in the loop.
// ---------------------------------------------------------------------------
__global__ __launch_bounds__(64)
void crf_scan_kernel(const float* __restrict__ e,
                     const float* __restrict__ Tmat,
                     const int*   __restrict__ tags,
                     float*       __restrict__ out_per_b)
{
    __shared__ float sT[SS * SS];
    const int tid = threadIdx.x;
    for (int i = tid; i < SS * SS; i += 64) sT[i] = Tmat[i];

    const int g   = tid >> 4;          // chain within wave
    const int to  = tid & 15;          // state owned by lane (0..10 real, 11..15 pad)
    const int toT = (to < SS) ? to : (SS - 1);       // clamped T column
    const int toE = (to < KTAGS) ? to : (KTAGS - 1); // clamped e column
    const int b   = blockIdx.x * GPW + g;

    __syncthreads();   // sT staged (only barrier; sT unused after init)

    // Rotation-indexed M: W[r] multiplies ror_r(alpha)[to] = alpha[(to - r) & 15].
    // (Verified rounds 5-8: absmax 0.0.)
    float W[16];
#pragma unroll
    for (int r = 0; r < 16; ++r) {
        const int f = (to - r) & 15;
        W[r] = (f < KTAGS && to <= SS - 1 && to != KTAGS)
                 ? __expf(sT[f * SS + toT]) : 0.f;
        if (to >= SS) W[r] = 0.f;
    }
    const float eTstop = __expf(sT[toT * SS + (SS - 1)]);

    const float* pe  = e    + (size_t)b * TT * KTAGS + toE;
    const int*   tgp = tags + (size_t)b * TT;

    // ---------------- t = 0 ----------------
    const float e0  = pe[0];
    const int   tg0 = tgp[0];
    float aP = (to < SS) ? __expf(sT[(SS - 2) * SS + toT] + e0) : 0.f;

    float cacc   = 0.f;                      // running log-scale (uniform in group)
    float em_acc = (to == tg0) ? e0 : 0.f;   // emission gather (one lane matches)

    // ---------------- pipelines: e lead = 16, tags lead = 16 ----------------
    float ebuf[UNR];
    int   tbuf[UNR];
#pragma unroll
    for (int j = 0; j < UNR; ++j) {
        ebuf[j] = pe[(size_t)(1 + j) * KTAGS];
        tbuf[j] = tgp[1 + j];
    }

    float scP = 1.f, eeP = 0.f;   // delayed exact power-of-two rescale

// Fused rotate-multiply-accumulate: 4 DPP muls + 12 DPP fmacs (verified).
// Rescale every 8 steps: apply at (J&7)==0, sample post-update at (J&7)==7.
// Growth bound ~2^13/step -> 2^104 over 8 steps < 2^127: exact, no overflow.
#define STEP(J, E_T, TG)                                                       \
    {                                                                          \
        const float X_T = __expf(E_T);   /* hides under the fmac chain */      \
        float ac0, ac1, ac2, ac3;                                              \
        asm volatile(                                                          \
          "s_nop 1\n\t"                                                        \
          "v_mul_f32 %0, %4, %5\n\t"                                           \
          "v_mul_f32_dpp %1, %4, %6  row_ror:1  row_mask:0xf bank_mask:0xf\n\t"\
          "v_mul_f32_dpp %2, %4, %7  row_ror:2  row_mask:0xf bank_mask:0xf\n\t"\
          "v_mul_f32_dpp %3, %4, %8  row_ror:3  row_mask:0xf bank_mask:0xf\n\t"\
          "v_fmac_f32_dpp %0, %4, %9  row_ror:4  row_mask:0xf bank_mask:0xf\n\t"\
          "v_fmac_f32_dpp %1, %4, %10 row_ror:5  row_mask:0xf bank_mask:0xf\n\t"\
          "v_fmac_f32_dpp %2, %4, %11 row_ror:6  row_mask:0xf bank_mask:0xf\n\t"\
          "v_fmac_f32_dpp %3, %4, %12 row_ror:7  row_mask:0xf bank_mask:0xf\n\t"\
          "v_fmac_f32_dpp %0, %4, %13 row_ror:8  row_mask:0xf bank_mask:0xf\n\t"\
          "v_fmac_f32_dpp %1, %4, %14 row_ror:9  row_mask:0xf bank_mask:0xf\n\t"\
          "v_fmac_f32_dpp %2, %4, %15 row_ror:10 row_mask:0xf bank_mask:0xf\n\t"\
          "v_fmac_f32_dpp %3, %4, %16 row_ror:11 row_mask:0xf bank_mask:0xf\n\t"\
          "v_fmac_f32_dpp %0, %4, %17 row_ror:12 row_mask:0xf bank_mask:0xf\n\t"\
          "v_fmac_f32_dpp %1, %4, %18 row_ror:13 row_mask:0xf bank_mask:0xf\n\t"\
          "v_fmac_f32_dpp %2, %4, %19 row_ror:14 row_mask:0xf bank_mask:0xf\n\t"\
          "v_fmac_f32_dpp %3, %4, %20 row_ror:15 row_mask:0xf bank_mask:0xf\n\t"\
          : "=&v"(ac0), "=&v"(ac1), "=&v"(ac2), "=&v"(ac3)                     \
          : "v"(aP), "v"(W[0]), "v"(W[1]), "v"(W[2]),  "v"(W[3]),              \
            "v"(W[4]), "v"(W[5]), "v"(W[6]),  "v"(W[7]), "v"(W[8]),            \
            "v"(W[9]), "v"(W[10]), "v"(W[11]), "v"(W[12]), "v"(W[13]),         \
            "v"(W[14]), "v"(W[15]));                                           \
        float xsc = X_T;                                                       \
        if (((J) & 7) == 0) { cacc += eeP * 0.6931471805599453f; xsc *= scP; } \
        aP = ((ac0 + ac1) + (ac2 + ac3)) * xsc;                                \
        if (((J) & 7) == 7) {   /* sample post-update alphas; apply at next (J&7)==0 */ \
            float mm;                                                          \
            asm volatile(                                                      \
              "s_nop 1\n\t"                                                    \
              "v_max_f32_dpp %0, %1, %1 row_ror:8 row_mask:0xf bank_mask:0xf\n\t"\
              "s_nop 1\n\t"                                                    \
              "v_max_f32_dpp %0, %0, %0 row_ror:4 row_mask:0xf bank_mask:0xf\n\t"\
              "s_nop 1\n\t"                                                    \
              "v_max_f32_dpp %0, %0, %0 quad_perm:[1,0,3,2] row_mask:0xf bank_mask:0xf\n\t"\
              "s_nop 1\n\t"                                                    \
              "v_max_f32_dpp %0, %0, %0 quad_perm:[2,3,0,1] row_mask:0xf bank_mask:0xf\n\t"\
              : "=&v"(mm) : "v"(aP));                                          \
            const int ee = (int)((__float_as_uint(mm) >> 23) & 0xFFu) - 127;   \
            scP = __uint_as_float((unsigned)(127 - ee) << 23);                 \
            eeP = (float)ee;                                                   \
        }                                                                      \
        em_acc += (to == (TG)) ? (E_T) : 0.f;                                  \
    }

    const float* qe = pe  + (size_t)(1 + UNR) * KTAGS;   // refill source: e[17...]
    const int*   qt = tgp + 1 + UNR;                      // refill source: tags[17...]

    // main loop: steps 1..992 (full refills valid)
    for (int tb = 1; tb + 2 * UNR <= TT; tb += UNR) {
#pragma unroll
        for (int j = 0; j < UNR; ++j) {
            const float E_T = ebuf[j];
            const int   TG  = tbuf[j];
            ebuf[j] = qe[j * KTAGS];          // e[t+16]
            tbuf[j] = qt[j];                  // tags[t+16]
            STEP(j, E_T, TG)
        }
        qe += (size_t)UNR * KTAGS; qt += UNR;
    }

    // penultimate block: steps 993..1008; refill only j<15 (t = 1009..1023)
#pragma unroll
    for (int j = 0; j < UNR; ++j) {
        const float E_T = ebuf[j];
        const int   TG  = tbuf[j];
        if (j < UNR - 1) {
            ebuf[j] = qe[j * KTAGS];
            tbuf[j] = qt[j];
        }
        STEP(j, E_T, TG)
    }

    // tail: steps 1009..1023 (j = 0..14)
#pragma unroll
    for (int j = 0; j < UNR - 1; ++j) {
        STEP(j, ebuf[j], tbuf[j])
    }
#undef STEP

    // ---------------- epilogue: 16-lane reductions ----------------
    float z  = (to < KTAGS) ? aP * eTstop : 0.f;
    float em = em_acc;
#pragma unroll
    for (int s = 8; s >= 1; s >>= 1) {
        z  += __shfl_xor(z,  s, 16);
        em += __shfl_xor(em, s, 16);
    }
    if (to == 0) {
        const float logZ = cacc + __logf(z);
        out_per_b[b] = logZ - em;     // gold transition/START/STOP terms subtracted by gold_kernel
    }
}

// ---------------------------------------------------------------------------
// Kernel 2: gold-path transition sum (parallel over b). Subtracts from ws[b].
// Runs after the scan on the same stream -> deterministic read-modify-write.
// ---------------------------------------------------------------------------
__global__ __launch_bounds__(64)
void gold_kernel(const float* __restrict__ Tmat,
                 const int*   __restrict__ tags,
                 float*       __restrict__ out_per_b)
{
    __shared__ float sT[SS * SS];
    __shared__ int   stg[TT];
    const int tid = threadIdx.x;
    const int b   = blockIdx.x;

    for (int i = tid; i < SS * SS; i += 64) sT[i] = Tmat[i];
    const int4* tg4 = (const int4*)(tags + (size_t)b * TT);
    int4* s4 = (int4*)stg;
#pragma unroll
    for (int k = 0; k < TT / 4 / 64; ++k) s4[tid + 64 * k] = tg4[tid + 64 * k];
    __syncthreads();

    // thread j sums transitions ending at t = 16j+1 .. 16j+16 (t <= 1023)
    float s = 0.f;
    const int t0 = tid * 16;
#pragma unroll
    for (int k = 1; k <= 16; ++k) {
        const int t = t0 + k;
        if (t < TT) s += sT[stg[t - 1] * SS + stg[t]];
    }
    if (tid == 0) {
        s += sT[(SS - 2) * SS + stg[0]];        // T[START, tag_0]
        s += sT[stg[TT - 1] * SS + (SS - 1)];   // T[tag_last, STOP]
    }
#pragma unroll
    for (int d = 32; d >= 1; d >>= 1) s += __shfl_xor(s, d, 64);
    if (tid == 0) out_per_b[b] -= s;
}

// Deterministic mean over B values (double accumulation).
__global__ __launch_bounds__(256)
void reduce_mean_kernel(const float* __restrict__ v, float* __restrict__ out, int n)
{
    __shared__ double sbuf[256];
    double s = 0.0;
    for (int i = threadIdx.x; i < n; i += 256) s += (double)v[i];
    sbuf[threadIdx.x] = s;
    __syncthreads();
    for (int k = 128; k > 0; k >>= 1) {
        if ((int)threadIdx.x < k) sbuf[threadIdx.x] += sbuf[threadIdx.x + k];
        __syncthreads();
    }
    if (threadIdx.x == 0) out[0] = (float)(sbuf[0] / (double)n);
}

extern "C" void kernel_launch(void* const* d_in, const int* in_sizes, int n_in,
                              void* d_out, int out_size, void* d_ws, size_t ws_size,
                              hipStream_t stream)
{
    const float* e    = (const float*)d_in[0];
    const float* Tmat = (const float*)d_in[1];
    const int*   tags = (const int*)d_in[2];
    // d_in[3] = mask: all-true in this problem; kernel implements the all-true path.

    float* ws  = (float*)d_ws;       // BB floats of scratch
    float* out = (float*)d_out;

    crf_scan_kernel<<<BB / GPW, 64, 0, stream>>>(e, Tmat, tags, ws);
    gold_kernel<<<BB, 64, 0, stream>>>(Tmat, tags, ws);
    reduce_mean_kernel<<<1, 256, 0, stream>>>(ws, out, BB);
}

// Round 10
// 80.514 us; speedup vs baseline: 2.9807x; 1.2031x over previous
//
#include <hip/hip_runtime.h>

#define KTAGS 11
#define SS    13
#define TT    1024
#define BB    4096
#define GPW   4      // chains per 64-thread block (16 lanes per chain)
#define UNR   16     // steps per unrolled block == e/tags pipeline depth
#define HALF  512    // split point: fwd covers t=0..511, bwd t=512..1023

// ws layout (floats)
#define WS_VA   0            // v = M^T a_511   [11][BB]
#define WS_UB   (11*BB)      // u_512 = x.b     [11][BB]
#define WS_CF   (22*BB)
#define WS_EF   (23*BB)
#define WS_CB   (24*BB)
#define WS_EB   (25*BB)
#define WS_NLL  (26*BB)
#define WS_FLOATS (27*BB)

// Fused rotate-multiply-accumulate: 4 DPP muls + 12 DPP fmacs (verified r5-r9).
// s_nop 1 covers VALU-write -> DPP-read hazard on SRC.
#define ROTSUM(A0,A1,A2,A3,SRC)                                                \
        asm volatile(                                                          \
          "s_nop 1\n\t"                                                        \
          "v_mul_f32 %0, %4, %5\n\t"                                           \
          "v_mul_f32_dpp %1, %4, %6  row_ror:1  row_mask:0xf bank_mask:0xf\n\t"\
          "v_mul_f32_dpp %2, %4, %7  row_ror:2  row_mask:0xf bank_mask:0xf\n\t"\
          "v_mul_f32_dpp %3, %4, %8  row_ror:3  row_mask:0xf bank_mask:0xf\n\t"\
          "v_fmac_f32_dpp %0, %4, %9  row_ror:4  row_mask:0xf bank_mask:0xf\n\t"\
          "v_fmac_f32_dpp %1, %4, %10 row_ror:5  row_mask:0xf bank_mask:0xf\n\t"\
          "v_fmac_f32_dpp %2, %4, %11 row_ror:6  row_mask:0xf bank_mask:0xf\n\t"\
          "v_fmac_f32_dpp %3, %4, %12 row_ror:7  row_mask:0xf bank_mask:0xf\n\t"\
          "v_fmac_f32_dpp %0, %4, %13 row_ror:8  row_mask:0xf bank_mask:0xf\n\t"\
          "v_fmac_f32_dpp %1, %4, %14 row_ror:9  row_mask:0xf bank_mask:0xf\n\t"\
          "v_fmac_f32_dpp %2, %4, %15 row_ror:10 row_mask:0xf bank_mask:0xf\n\t"\
          "v_fmac_f32_dpp %3, %4, %16 row_ror:11 row_mask:0xf bank_mask:0xf\n\t"\
          "v_fmac_f32_dpp %0, %4, %17 row_ror:12 row_mask:0xf bank_mask:0xf\n\t"\
          "v_fmac_f32_dpp %1, %4, %18 row_ror:13 row_mask:0xf bank_mask:0xf\n\t"\
          "v_fmac_f32_dpp %2, %4, %19 row_ror:14 row_mask:0xf bank_mask:0xf\n\t"\
          "v_fmac_f32_dpp %3, %4, %20 row_ror:15 row_mask:0xf bank_mask:0xf\n\t"\
          : "=&v"(A0), "=&v"(A1), "=&v"(A2), "=&v"(A3)                         \
          : "v"(SRC), "v"(W[0]), "v"(W[1]), "v"(W[2]),  "v"(W[3]),             \
            "v"(W[4]), "v"(W[5]), "v"(W[6]),  "v"(W[7]), "v"(W[8]),            \
            "v"(W[9]), "v"(W[10]), "v"(W[11]), "v"(W[12]), "v"(W[13]),         \
            "v"(W[14]), "v"(W[15]))

#define MAXRED(MM, SRC)                                                        \
        asm volatile(                                                          \
          "s_nop 1\n\t"                                                        \
          "v_max_f32_dpp %0, %1, %1 row_ror:8 row_mask:0xf bank_mask:0xf\n\t"  \
          "s_nop 1\n\t"                                                        \
          "v_max_f32_dpp %0, %0, %0 row_ror:4 row_mask:0xf bank_mask:0xf\n\t"  \
          "s_nop 1\n\t"                                                        \
          "v_max_f32_dpp %0, %0, %0 quad_perm:[1,0,3,2] row_mask:0xf bank_mask:0xf\n\t"\
          "s_nop 1\n\t"                                                        \
          "v_max_f32_dpp %0, %0, %0 quad_perm:[2,3,0,1] row_mask:0xf bank_mask:0xf\n\t"\
          : "=&v"(MM) : "v"(SRC))

// Rescale every 8 steps: apply pending at (J&7)==0, sample post-update at (J&7)==7.
#define STEP(J, E_T, TG)                                                       \
    {                                                                          \
        const float X_T = __expf(E_T);                                         \
        float ac0, ac1, ac2, ac3;                                              \
        ROTSUM(ac0, ac1, ac2, ac3, aP);                                        \
        float xsc = X_T;                                                       \
        if (((J) & 7) == 0) { cacc += eeP * 0.6931471805599453f; xsc *= scP; } \
        aP = ((ac0 + ac1) + (ac2 + ac3)) * xsc;                                \
        if (((J) & 7) == 7) {                                                  \
            float mm;                                                          \
            MAXRED(mm, aP);                                                    \
            const int ee = (int)((__float_as_uint(mm) >> 23) & 0xFFu) - 127;   \
            scP = __uint_as_float((unsigned)(127 - ee) << 23);                 \
            eeP = (float)ee;                                                   \
        }                                                                      \
        em_acc += (to == (TG)) ? (E_T) : 0.f;                                  \
    }

// ---------------------------------------------------------------------------
// Half-scan: DIR=+1 -> forward t=0..511, emits v = M^T a_511, cacc_f, em_f.
//            DIR=-1 -> backward t=1023..512, emits u_512, cacc_b, em_b.
// ---------------------------------------------------------------------------
template<int DIR>
__device__ __forceinline__ void scan_dir(const float* __restrict__ e,
                                         const int*   __restrict__ tags,
                                         const float* sT,
                                         float*       __restrict__ ws,
                                         int b, int to)
{
    const int toT = (to < SS) ? to : (SS - 1);
    const int toE = (to < KTAGS) ? to : (KTAGS - 1);

    float W[16];
#pragma unroll
    for (int r = 0; r < 16; ++r) {
        const int f = (to - r) & 15;
        if (DIR > 0) {
            W[r] = (f < KTAGS && to <= SS - 1 && to != KTAGS)
                     ? __expf(sT[f * SS + toT]) : 0.f;
            if (to >= SS) W[r] = 0.f;
        } else {
            W[r] = (to < KTAGS && f < KTAGS) ? __expf(sT[to * SS + f]) : 0.f;
        }
    }

    const float* ebase = e    + (size_t)b * TT * KTAGS + toE;
    const int*   tbase = tags + (size_t)b * TT;

    float aP, em_acc, cacc = 0.f;
    if (DIR > 0) {
        const float E0 = ebase[0];
        const int   tg0 = tbase[0];
        aP = (to < SS) ? __expf(sT[(SS - 2) * SS + toT] + E0) : 0.f;
        em_acc = (to == tg0) ? E0 : 0.f;
    } else {
        const float E0 = ebase[(size_t)(TT - 1) * KTAGS];
        const int   tg0 = tbase[TT - 1];
        // u_1023 = x_1023 * exp(T[to, STOP]); pad lanes exactly 0
        aP = (to < KTAGS) ? __expf(E0 + sT[toT * SS + (SS - 1)]) : 0.f;
        em_acc = (to == tg0) ? E0 : 0.f;
    }

    // update j (0..510) consumes e/tag at t = DIR>0 ? 1+j : 1022-j
    const ptrdiff_t estep = (ptrdiff_t)DIR * KTAGS;
    const float* peU = ebase + ((DIR > 0) ? (ptrdiff_t)KTAGS : (ptrdiff_t)(TT - 2) * KTAGS);
    const int*   tgU = tbase + ((DIR > 0) ? 1 : (TT - 2));

    float ebuf[UNR]; int tbuf[UNR];
#pragma unroll
    for (int j = 0; j < UNR; ++j) {
        ebuf[j] = peU[estep * j];
        tbuf[j] = tgU[DIR * j];
    }

    float scP = 1.f, eeP = 0.f;
    const float* qe = peU + estep * UNR;
    const int*   qt = tgU + DIR * UNR;

    // main: updates 0..479 (refills 16..495 valid)
    for (int tb = 0; tb + 2 * UNR <= (HALF - 1); tb += UNR) {
#pragma unroll
        for (int j = 0; j < UNR; ++j) {
            const float E_T = ebuf[j];
            const int   TG  = tbuf[j];
            ebuf[j] = qe[estep * j];
            tbuf[j] = qt[DIR * j];
            STEP(j, E_T, TG)
        }
        qe += estep * UNR; qt += DIR * UNR;
    }
    // penultimate: updates 480..495; refill j<15 (496..510)
#pragma unroll
    for (int j = 0; j < UNR; ++j) {
        const float E_T = ebuf[j];
        const int   TG  = tbuf[j];
        if (j < UNR - 1) { ebuf[j] = qe[estep * j]; tbuf[j] = qt[DIR * j]; }
        STEP(j, E_T, TG)
    }
    // tail: updates 496..510
#pragma unroll
    for (int j = 0; j < UNR - 1; ++j) {
        STEP(j, ebuf[j], tbuf[j])
    }

    // epilogue: group-sum em; write vectors + scalars
    float em = em_acc;
#pragma unroll
    for (int s = 8; s >= 1; s >>= 1) em += __shfl_xor(em, s, 16);

    if (DIR > 0) {
        float ac0, ac1, ac2, ac3;
        ROTSUM(ac0, ac1, ac2, ac3, aP);       // v = M^T a_511 (no x multiply)
        const float v = (ac0 + ac1) + (ac2 + ac3);
        if (to < KTAGS) ws[WS_VA + to * BB + b] = v;
        if (to == 0) { ws[WS_CF + b] = cacc; ws[WS_EF + b] = em; }
    } else {
        if (to < KTAGS) ws[WS_UB + to * BB + b] = aP;
        if (to == 0) { ws[WS_CB + b] = cacc; ws[WS_EB + b] = em; }
    }
}

__global__ __launch_bounds__(64)
void crf_scan2_kernel(const float* __restrict__ e,
                      const float* __restrict__ Tmat,
                      const int*   __restrict__ tags,
                      float*       __restrict__ ws)
{
    __shared__ float sT[SS * SS];
    const int tid = threadIdx.x;
    for (int i = tid; i < SS * SS; i += 64) sT[i] = Tmat[i];
    __syncthreads();

    const int g  = tid >> 4;
    const int to = tid & 15;
    const int b  = ((int)blockIdx.x & (BB / GPW - 1)) * GPW + g;

    if ((int)blockIdx.x < BB / GPW) scan_dir<+1>(e, tags, sT, ws, b, to);
    else                            scan_dir<-1>(e, tags, sT, ws, b, to);
}

// combine: nll[b] = cacc_f + cacc_b + log(v.u) - em_f - em_b   (dot in double)
__global__ __launch_bounds__(256)
void combine_kernel(float* __restrict__ ws)
{
    const int b = blockIdx.x * 256 + threadIdx.x;
    double dot = 0.0;
#pragma unroll
    for (int s = 0; s < KTAGS; ++s)
        dot += (double)ws[WS_VA + s * BB + b] * (double)ws[WS_UB + s * BB + b];
    const float logZ = (float)((double)ws[WS_CF + b] + (double)ws[WS_CB + b] + log(dot));
    ws[WS_NLL + b] = logZ - ws[WS_EF + b] - ws[WS_EB + b];
}

// gold transition/START/STOP sum, subtracted from nll[b]
__global__ __launch_bounds__(64)
void gold_kernel(const float* __restrict__ Tmat,
                 const int*   __restrict__ tags,
                 float*       __restrict__ nll)
{
    __shared__ float sT[SS * SS];
    __shared__ int   stg[TT];
    const int tid = threadIdx.x;
    const int b   = blockIdx.x;

    for (int i = tid; i < SS * SS; i += 64) sT[i] = Tmat[i];
    const int4* tg4 = (const int4*)(tags + (size_t)b * TT);
    int4* s4 = (int4*)stg;
#pragma unroll
    for (int k = 0; k < TT / 4 / 64; ++k) s4[tid + 64 * k] = tg4[tid + 64 * k];
    __syncthreads();

    float s = 0.f;
    const int t0 = tid * 16;
#pragma unroll
    for (int k = 1; k <= 16; ++k) {
        const int t = t0 + k;
        if (t < TT) s += sT[stg[t - 1] * SS + stg[t]];
    }
    if (tid == 0) {
        s += sT[(SS - 2) * SS + stg[0]];
        s += sT[stg[TT - 1] * SS + (SS - 1)];
    }
#pragma unroll
    for (int d = 32; d >= 1; d >>= 1) s += __shfl_xor(s, d, 64);
    if (tid == 0) nll[b] -= s;
}

__global__ __launch_bounds__(256)
void reduce_mean_kernel(const float* __restrict__ v, float* __restrict__ out, int n)
{
    __shared__ double sbuf[256];
    double s = 0.0;
    for (int i = threadIdx.x; i < n; i += 256) s += (double)v[i];
    sbuf[threadIdx.x] = s;
    __syncthreads();
    for (int k = 128; k > 0; k >>= 1) {
        if ((int)threadIdx.x < k) sbuf[threadIdx.x] += sbuf[threadIdx.x + k];
        __syncthreads();
    }
    if (threadIdx.x == 0) out[0] = (float)(sbuf[0] / (double)n);
}

// ---------------------------------------------------------------------------
// Fallback (round-9 verified): full forward scan, used only if ws is too small.
// ---------------------------------------------------------------------------
__global__ __launch_bounds__(64)
void crf_scan_full_kernel(const float* __restrict__ e,
                          const float* __restrict__ Tmat,
                          const int*   __restrict__ tags,
                          float*       __restrict__ out_per_b)
{
    __shared__ float sT[SS * SS];
    const int tid = threadIdx.x;
    for (int i = tid; i < SS * SS; i += 64) sT[i] = Tmat[i];

    const int g   = tid >> 4;
    const int to  = tid & 15;
    const int toT = (to < SS) ? to : (SS - 1);
    const int toE = (to < KTAGS) ? to : (KTAGS - 1);
    const int b   = blockIdx.x * GPW + g;
    __syncthreads();

    float W[16];
#pragma unroll
    for (int r = 0; r < 16; ++r) {
        const int f = (to - r) & 15;
        W[r] = (f < KTAGS && to <= SS - 1 && to != KTAGS)
                 ? __expf(sT[f * SS + toT]) : 0.f;
        if (to >= SS) W[r] = 0.f;
    }
    const float eTstop = __expf(sT[toT * SS + (SS - 1)]);

    const float* pe  = e    + (size_t)b * TT * KTAGS + toE;
    const int*   tgp = tags + (size_t)b * TT;

    const float e0  = pe[0];
    const int   tg0 = tgp[0];
    float aP = (to < SS) ? __expf(sT[(SS - 2) * SS + toT] + e0) : 0.f;
    float cacc = 0.f;
    float em_acc = (to == tg0) ? e0 : 0.f;

    float ebuf[UNR]; int tbuf[UNR];
#pragma unroll
    for (int j = 0; j < UNR; ++j) {
        ebuf[j] = pe[(size_t)(1 + j) * KTAGS];
        tbuf[j] = tgp[1 + j];
    }
    float scP = 1.f, eeP = 0.f;

    const float* qe = pe  + (size_t)(1 + UNR) * KTAGS;
    const int*   qt = tgp + 1 + UNR;
    for (int tb = 1; tb + 2 * UNR <= TT; tb += UNR) {
#pragma unroll
        for (int j = 0; j < UNR; ++j) {
            const float E_T = ebuf[j];
            const int   TG  = tbuf[j];
            ebuf[j] = qe[j * KTAGS];
            tbuf[j] = qt[j];
            STEP(j, E_T, TG)
        }
        qe += (size_t)UNR * KTAGS; qt += UNR;
    }
#pragma unroll
    for (int j = 0; j < UNR; ++j) {
        const float E_T = ebuf[j];
        const int   TG  = tbuf[j];
        if (j < UNR - 1) { ebuf[j] = qe[j * KTAGS]; tbuf[j] = qt[j]; }
        STEP(j, E_T, TG)
    }
#pragma unroll
    for (int j = 0; j < UNR - 1; ++j) {
        STEP(j, ebuf[j], tbuf[j])
    }

    float z  = (to < KTAGS) ? aP * eTstop : 0.f;
    float em = em_acc;
#pragma unroll
    for (int s = 8; s >= 1; s >>= 1) {
        z  += __shfl_xor(z,  s, 16);
        em += __shfl_xor(em, s, 16);
    }
    if (to == 0) {
        const float logZ = cacc + __logf(z);
        out_per_b[b] = logZ - em;
    }
}

extern "C" void kernel_launch(void* const* d_in, const int* in_sizes, int n_in,
                              void* d_out, int out_size, void* d_ws, size_t ws_size,
                              hipStream_t stream)
{
    const float* e    = (const float*)d_in[0];
    const float* Tmat = (const float*)d_in[1];
    const int*   tags = (const int*)d_in[2];
    // d_in[3] = mask: all-true in this problem; kernel implements the all-true path.

    float* ws  = (float*)d_ws;
    float* out = (float*)d_out;

    if (ws_size >= (size_t)WS_FLOATS * sizeof(float)) {
        crf_scan2_kernel<<<2 * BB / GPW, 64, 0, stream>>>(e, Tmat, tags, ws);
        combine_kernel<<<BB / 256, 256, 0, stream>>>(ws);
        gold_kernel<<<BB, 64, 0, stream>>>(Tmat, tags, ws + WS_NLL);
        reduce_mean_kernel<<<1, 256, 0, stream>>>(ws + WS_NLL, out, BB);
    } else {
        crf_scan_full_kernel<<<BB / GPW, 64, 0, stream>>>(e, Tmat, tags, ws);
        gold_kernel<<<BB, 64, 0, stream>>>(Tmat, tags, ws);
        reduce_mean_kernel<<<1, 256, 0, stream>>>(ws, out, BB);
    }
}